// Round 4
// baseline (787.629 us; speedup 1.0000x reference)
//
#include <hip/hip_runtime.h>
#include <hip/hip_bf16.h>
#include <stdint.h>

#define NB 16
#define NPT 2048
#define NS 512
#define NK 32
#define PTOT (NB*NS*NK)   // 262144 positions
#define C_IN 67
#define EPSV 1e-5f

// ws layout (float indices)
#define WS_NEWXYZ 0            // 24576
#define WS_GIDX   24576        // ints, 262144 -> 286720
#define WS_STATS  286720       // 1024: sum0@0 sq0@64 sum1@128 sq1@192 sum2@256 sq2@384 aff@512..1024
#define WS_RAWMAX 294912       // 128*8192 = 1048576 -> 1343488
#define WS_PTS_T  1343488      // 2097152 -> 3440640
#define WS_Y1     3440640      // 64*PTOT fp32 = 16777216 -> 20217856 (y3 bf16 overlays this)
#define WS_Y2     20217856     // 16777216 -> 36995072 floats (148MB)

// ---- single-instruction-per-step DPP u32 max (dist bits of non-negative floats) ----
template<int CTRL>
__device__ __forceinline__ uint32_t dppumax(uint32_t v){
  int o = __builtin_amdgcn_update_dpp((int)v, (int)v, CTRL, 0xF, 0xF, false);
  uint32_t ov = (uint32_t)o;
  return ov > v ? ov : v;
}

// ---------------- FPS: 256 threads, 8 pts/thread ----------------
// wave reduce: u32 DPP max on dist bits -> ballots to recover first-index argmax
// cross-wave: winning lane ships xyz+key through LDS (no per-point LDS table needed)
__global__ __launch_bounds__(256) void fps_kernel(const float* __restrict__ xyz,
                                                  float* __restrict__ nxyz,
                                                  float* __restrict__ out0)
{
  __shared__ __align__(16) float4 warrA[2][4];   // xyz + dist-bits of wave candidate
  __shared__ __align__(16) int    warrB[2][4];   // candidate global n (tie-break)
  __shared__ __align__(16) float4 csel[NS];      // selected centroids (epilogue)
  const int b = blockIdx.x;
  const int tid = threadIdx.x;
  const int lane = tid & 63, wid = tid >> 6;
  const float* xb = xyz + (size_t)b*3*NPT;
  float px[8], py[8], pz[8], dist[8];
  #pragma unroll
  for (int j=0;j<8;j++){
    int n = j*256 + tid;
    px[j]=xb[n]; py[j]=xb[NPT+n]; pz[j]=xb[2*NPT+n];
    dist[j]=1e10f;
  }
  float cx = xb[0], cy = xb[NPT], cz = xb[2*NPT];   // centroid 0 = point 0
  if (tid==0) csel[0] = make_float4(cx,cy,cz,0.f);
  for (int t=1;t<NS;t++){
    #pragma unroll
    for (int j=0;j<8;j++){
      float dx = __fsub_rn(px[j], cx);
      float dy = __fsub_rn(py[j], cy);
      float dz = __fsub_rn(pz[j], cz);
      float d  = __fadd_rn(__fadd_rn(__fmul_rn(dx,dx),__fmul_rn(dy,dy)),__fmul_rn(dz,dz));
      dist[j] = fminf(dist[j], d);
    }
    // lane max (float max == u32 max for non-negatives)
    float lm = fmaxf(fmaxf(fmaxf(dist[0],dist[1]), fmaxf(dist[2],dist[3])),
                     fmaxf(fmaxf(dist[4],dist[5]), fmaxf(dist[6],dist[7])));
    uint32_t mb = __float_as_uint(lm);
    mb = dppumax<0xB1>(mb);    // quad xor1
    mb = dppumax<0x4E>(mb);    // quad xor2
    mb = dppumax<0x124>(mb);   // row_ror:4
    mb = dppumax<0x128>(mb);   // row_ror:8   -> row16 max everywhere
    mb = dppumax<0x142>(mb);   // row_bcast15
    mb = dppumax<0x143>(mb);   // row_bcast31 -> lane63 holds wave max
    const uint32_t m = (uint32_t)__builtin_amdgcn_readlane((int)mb, 63);  // uniform
    // recover first-index argmax within wave
    unsigned long long bal[8];
    #pragma unroll
    for (int j=0;j<8;j++) bal[j] = __ballot(__float_as_uint(dist[j]) == m);
    int jwin = 0; unsigned long long balwin = 0;
    #pragma unroll
    for (int j=7;j>=0;j--){ if (bal[j]){ jwin = j; balwin = bal[j]; } }
    const int winlane = __ffsll(balwin) - 1;
    const int cand = jwin*256 + wid*64 + winlane;   // global n of wave candidate
    // winning lane selects its coords (jwin uniform)
    float sx = px[0], sy = py[0], sz = pz[0];
    #pragma unroll
    for (int j=1;j<8;j++){ if (jwin==j){ sx=px[j]; sy=py[j]; sz=pz[j]; } }
    const int tb = t & 1;
    if (lane == winlane){
      warrA[tb][wid] = make_float4(sx, sy, sz, __uint_as_float(m));
      warrB[tb][wid] = cand;
    }
    __syncthreads();
    float4 A0 = warrA[tb][0], A1 = warrA[tb][1], A2 = warrA[tb][2], A3 = warrA[tb][3];
    int4 C4 = *(const int4*)&warrB[tb][0];
    unsigned long long k0 = (((unsigned long long)__float_as_uint(A0.w))<<32) | (uint32_t)~C4.x;
    unsigned long long k1 = (((unsigned long long)__float_as_uint(A1.w))<<32) | (uint32_t)~C4.y;
    unsigned long long k2 = (((unsigned long long)__float_as_uint(A2.w))<<32) | (uint32_t)~C4.z;
    unsigned long long k3 = (((unsigned long long)__float_as_uint(A3.w))<<32) | (uint32_t)~C4.w;
    if (k1 > k0){ k0 = k1; A0 = A1; }
    if (k3 > k2){ k2 = k3; A2 = A3; }
    if (k2 > k0){ k0 = k2; A0 = A2; }
    cx = A0.x; cy = A0.y; cz = A0.z;
    if (tid==0) csel[t] = make_float4(cx,cy,cz,0.f);
  }
  __syncthreads();
  // epilogue: write new_xyz (ws) and output0
  for (int s = tid; s < NS; s += 256){
    float4 cc = csel[s];
    float* np_ = nxyz + ((size_t)b*NS + s)*3;
    np_[0]=cc.x; np_[1]=cc.y; np_[2]=cc.z;
    float* ob = out0 + (size_t)b*3*NS + s;
    ob[0]=cc.x; ob[NS]=cc.y; ob[2*NS]=cc.z;
  }
}

// ---------------- ball query: one wave per group ----------------
__global__ __launch_bounds__(256) void ballq_kernel(const float* __restrict__ xyz,
                                                    const float* __restrict__ nxyz,
                                                    int* __restrict__ gidx)
{
  const int g = blockIdx.x*4 + (threadIdx.x>>6);
  const int lane = threadIdx.x & 63;
  const int b = g >> 9;
  const float* xb = xyz + (size_t)b*3*NPT;
  const float* c = nxyz + (size_t)g*3;
  const float cx = c[0], cy = c[1], cz = c[2];
  const float r2 = 0.2f*0.2f;
  int cnt = 0; int first = 0;
  int* out = gidx + (size_t)g*NK;
  for (int ch=0; ch<NPT/64 && cnt<NK; ch++){
    int n = ch*64 + lane;
    float dx = __fsub_rn(cx, xb[n]);
    float dy = __fsub_rn(cy, xb[NPT+n]);
    float dz = __fsub_rn(cz, xb[2*NPT+n]);
    float d  = __fadd_rn(__fadd_rn(__fmul_rn(dx,dx),__fmul_rn(dy,dy)),__fmul_rn(dz,dz));
    bool in = (d <= r2);
    unsigned long long mask = __ballot(in);
    if (mask){
      if (cnt==0) first = ch*64 + (__ffsll((unsigned long long)mask)-1);
      if (in){
        int pos = cnt + __popcll(mask & ((1ull<<lane)-1ull));
        if (pos < NK) out[pos] = n;
      }
      cnt += __popcll(mask);
    }
  }
  if (cnt < NK && lane >= cnt && lane < NK) out[lane] = first;
}

// ---------------- transpose points (B,64,N) -> (B,N,64) ----------------
__global__ __launch_bounds__(256) void transpose_kernel(const float* __restrict__ pts,
                                                        float* __restrict__ pts_t)
{
  __shared__ float tile[64][65];
  const int blk = blockIdx.x;          // B * N/64 = 512
  const int b = blk >> 5;
  const int n0 = (blk & 31) * 64;
  const int lane = threadIdx.x & 63;
  const int row4 = threadIdx.x >> 6;
  const float* src = pts + (size_t)b*64*NPT;
  #pragma unroll
  for (int r=0; r<16; r++){
    int cc = r*4 + row4;
    tile[cc][lane] = src[(size_t)cc*NPT + n0 + lane];
  }
  __syncthreads();
  float* dst = pts_t + ((size_t)b*NPT + n0)*64;
  #pragma unroll
  for (int r=0; r<16; r++){
    int nn = r*4 + row4;
    dst[(size_t)nn*64 + lane] = tile[lane][nn];
  }
}

// ---------------- conv1: gather + 67->64 ----------------
__global__ __launch_bounds__(256) void conv1_kernel(const float* __restrict__ xyz,
    const float* __restrict__ pts_t, const int* __restrict__ gidx,
    const float* __restrict__ nxyz, const float* __restrict__ Wt,
    const float* __restrict__ bias, float* __restrict__ y)
{
  const int p = blockIdx.x*256 + threadIdx.x;
  const int bs = p >> 5;
  const int b = p >> 14;
  const int n = gidx[p];
  float x[C_IN];
  {
    const float* xb = xyz + (size_t)b*3*NPT;
    const float* cc = nxyz + (size_t)bs*3;
    x[0] = xb[n]        - cc[0];
    x[1] = xb[NPT+n]    - cc[1];
    x[2] = xb[2*NPT+n]  - cc[2];
    const float4* pr = (const float4*)(pts_t + ((size_t)b*NPT + n)*64);
    #pragma unroll
    for (int q=0;q<16;q++){
      float4 v = pr[q];
      x[3+4*q]=v.x; x[4+4*q]=v.y; x[5+4*q]=v.z; x[6+4*q]=v.w;
    }
  }
  #pragma unroll 1
  for (int o=0;o<64;o+=4){
    float a0=bias[o+0], a1=bias[o+1], a2=bias[o+2], a3=bias[o+3];
    #pragma unroll
    for (int c=0;c<C_IN;c++){
      float xv = x[c];
      a0 = fmaf(Wt[(o+0)*C_IN+c], xv, a0);
      a1 = fmaf(Wt[(o+1)*C_IN+c], xv, a1);
      a2 = fmaf(Wt[(o+2)*C_IN+c], xv, a2);
      a3 = fmaf(Wt[(o+3)*C_IN+c], xv, a3);
    }
    y[(size_t)(o+0)*PTOT+p]=a0; y[(size_t)(o+1)*PTOT+p]=a1;
    y[(size_t)(o+2)*PTOT+p]=a2; y[(size_t)(o+3)*PTOT+p]=a3;
  }
}

// ---------------- conv2: affine+relu in, 64->64 ----------------
__global__ __launch_bounds__(256) void conv2_kernel(const float* __restrict__ yin,
    const float* __restrict__ affA, const float* __restrict__ affB,
    const float* __restrict__ Wt, const float* __restrict__ bias,
    float* __restrict__ yout)
{
  const int p = blockIdx.x*256 + threadIdx.x;
  float x[64];
  #pragma unroll
  for (int c=0;c<64;c++){
    float v = yin[(size_t)c*PTOT + p];
    x[c] = fmaxf(fmaf(v, affA[c], affB[c]), 0.f);
  }
  #pragma unroll 1
  for (int o=0;o<64;o+=4){
    float a0=bias[o+0], a1=bias[o+1], a2=bias[o+2], a3=bias[o+3];
    #pragma unroll
    for (int c=0;c<64;c++){
      float xv = x[c];
      a0 = fmaf(Wt[(o+0)*64+c], xv, a0);
      a1 = fmaf(Wt[(o+1)*64+c], xv, a1);
      a2 = fmaf(Wt[(o+2)*64+c], xv, a2);
      a3 = fmaf(Wt[(o+3)*64+c], xv, a3);
    }
    yout[(size_t)(o+0)*PTOT+p]=a0; yout[(size_t)(o+1)*PTOT+p]=a1;
    yout[(size_t)(o+2)*PTOT+p]=a2; yout[(size_t)(o+3)*PTOT+p]=a3;
  }
}

// ---------------- conv3: 64->128, bf16 output ----------------
__global__ __launch_bounds__(256) void conv3_kernel(const float* __restrict__ yin,
    const float* __restrict__ affA, const float* __restrict__ affB,
    const float* __restrict__ Wt, const float* __restrict__ bias,
    __hip_bfloat16* __restrict__ y3b)
{
  const int p = blockIdx.x*256 + threadIdx.x;
  float x[64];
  #pragma unroll
  for (int c=0;c<64;c++){
    float v = yin[(size_t)c*PTOT + p];
    x[c] = fmaxf(fmaf(v, affA[c], affB[c]), 0.f);
  }
  #pragma unroll 1
  for (int o=0;o<128;o+=4){
    float a0=bias[o+0], a1=bias[o+1], a2=bias[o+2], a3=bias[o+3];
    #pragma unroll
    for (int c=0;c<64;c++){
      float xv = x[c];
      a0 = fmaf(Wt[(o+0)*64+c], xv, a0);
      a1 = fmaf(Wt[(o+1)*64+c], xv, a1);
      a2 = fmaf(Wt[(o+2)*64+c], xv, a2);
      a3 = fmaf(Wt[(o+3)*64+c], xv, a3);
    }
    y3b[(size_t)(o+0)*PTOT+p]=__float2bfloat16(a0);
    y3b[(size_t)(o+1)*PTOT+p]=__float2bfloat16(a1);
    y3b[(size_t)(o+2)*PTOT+p]=__float2bfloat16(a2);
    y3b[(size_t)(o+3)*PTOT+p]=__float2bfloat16(a3);
  }
}

// ---------------- per-channel sum / sumsq ----------------
__global__ __launch_bounds__(256) void stats_kernel(const float* __restrict__ y,
                                                    float* __restrict__ sum,
                                                    float* __restrict__ sumsq)
{
  const int c = blockIdx.x;
  const float* yc = y + (size_t)c*PTOT + (size_t)blockIdx.y*8192;
  float s=0.f, s2=0.f;
  #pragma unroll 4
  for (int it=0; it<32; it++){
    float v = yc[it*256 + threadIdx.x];
    s += v; s2 = fmaf(v, v, s2);
  }
  #pragma unroll
  for (int off=32; off>0; off>>=1){ s += __shfl_down(s,off,64); s2 += __shfl_down(s2,off,64); }
  __shared__ float rs[4], rs2[4];
  const int lane = threadIdx.x&63, wid = threadIdx.x>>6;
  if (lane==0){ rs[wid]=s; rs2[wid]=s2; }
  __syncthreads();
  if (threadIdx.x==0){
    atomicAdd(sum+c,   rs[0]+rs[1]+rs[2]+rs[3]);
    atomicAdd(sumsq+c, rs2[0]+rs2[1]+rs2[2]+rs2[3]);
  }
}

// ---------------- fused stats + K-maxpool over bf16 y3 ----------------
__global__ __launch_bounds__(256) void statsmax_kernel(const __hip_bfloat16* __restrict__ y3b,
    float* __restrict__ sum, float* __restrict__ sumsq, float* __restrict__ rawmax)
{
  const int c = blockIdx.x;
  const int py0 = blockIdx.y*16384;               // position base
  const ushort* yc = (const ushort*)(y3b + (size_t)c*PTOT + py0);
  const int lane = threadIdx.x & 63, wid = threadIdx.x >> 6;
  const int grp = lane >> 3, sub = lane & 7;      // 8 lanes per bs-group
  float s=0.f, s2=0.f;
  #pragma unroll 2
  for (int it=0; it<16; it++){
    int bsl = it*32 + wid*8 + grp;                // local bs 0..511
    ushort4 v = *((const ushort4*)(yc + bsl*32) + sub);
    float f0 = __uint_as_float((uint32_t)v.x<<16);
    float f1 = __uint_as_float((uint32_t)v.y<<16);
    float f2 = __uint_as_float((uint32_t)v.z<<16);
    float f3 = __uint_as_float((uint32_t)v.w<<16);
    s  += f0+f1+f2+f3;
    s2 += f0*f0+f1*f1+f2*f2+f3*f3;
    float m = fmaxf(fmaxf(f0,f1), fmaxf(f2,f3));
    m = fmaxf(m, __shfl_xor(m,1,64));
    m = fmaxf(m, __shfl_xor(m,2,64));
    m = fmaxf(m, __shfl_xor(m,4,64));
    if (sub==0) rawmax[(size_t)c*8192 + (py0>>5) + bsl] = m;
  }
  #pragma unroll
  for (int off=32; off>0; off>>=1){ s += __shfl_down(s,off,64); s2 += __shfl_down(s2,off,64); }
  __shared__ float rs[4], rs2[4];
  if (lane==0){ rs[wid]=s; rs2[wid]=s2; }
  __syncthreads();
  if (threadIdx.x==0){
    atomicAdd(sum+c,   rs[0]+rs[1]+rs[2]+rs[3]);
    atomicAdd(sumsq+c, rs2[0]+rs2[1]+rs2[2]+rs2[3]);
  }
}

__global__ void affine_kernel(const float* __restrict__ sum, const float* __restrict__ sumsq,
                              const float* __restrict__ g, const float* __restrict__ bt,
                              float* __restrict__ affA, float* __restrict__ affB, int C)
{
  int c = threadIdx.x;
  if (c < C){
    float mean = sum[c] * (1.f/PTOT);
    float var  = sumsq[c] * (1.f/PTOT) - mean*mean;
    float a = g[c] * rsqrtf(var + EPSV);
    affA[c] = a;
    affB[c] = fmaf(-mean, a, bt[c]);
  }
}

// ---------------- finalize: affine+relu on raw maxima ----------------
__global__ __launch_bounds__(256) void finalize_kernel(const float* __restrict__ rawmax,
    const float* __restrict__ affA, const float* __restrict__ affB,
    float* __restrict__ out)
{
  int i = blockIdx.x*256 + threadIdx.x;  // over 128*8192
  int c = i >> 13, r = i & 8191, b = r >> 9, s = r & 511;
  float a = affA[c], bb = affB[c];
  out[((size_t)(b*128+c))*512 + s] = fmaxf(fmaf(rawmax[i], a, bb), 0.f);
}

__global__ void zero_kernel(float* p){ p[blockIdx.x*256 + threadIdx.x] = 0.f; }

extern "C" void kernel_launch(void* const* d_in, const int* in_sizes, int n_in,
                              void* d_out, int out_size, void* d_ws, size_t ws_size,
                              hipStream_t stream) {
  const float* xyz = (const float*)d_in[0];
  const float* pts = (const float*)d_in[1];
  const float* w0  = (const float*)d_in[2];
  const float* b0  = (const float*)d_in[3];
  const float* g0  = (const float*)d_in[4];
  const float* bt0 = (const float*)d_in[5];
  const float* w1  = (const float*)d_in[6];
  const float* b1  = (const float*)d_in[7];
  const float* g1  = (const float*)d_in[8];
  const float* bt1 = (const float*)d_in[9];
  const float* w2  = (const float*)d_in[10];
  const float* b2  = (const float*)d_in[11];
  const float* g2  = (const float*)d_in[12];
  const float* bt2 = (const float*)d_in[13];
  float* out = (float*)d_out;
  float* ws  = (float*)d_ws;

  float* nxyz   = ws + WS_NEWXYZ;
  int*   gidx   = (int*)(ws + WS_GIDX);
  float* st     = ws + WS_STATS;
  float *sum0=st,     *sq0=st+64;
  float *sum1=st+128, *sq1=st+192;
  float *sum2=st+256, *sq2=st+384;
  float *aA0=st+512, *aB0=st+576, *aA1=st+640, *aB1=st+704;
  float *aA2=st+768, *aB2=st+896;
  float* rawmax = ws + WS_RAWMAX;
  float* pts_t  = ws + WS_PTS_T;
  float* y1     = ws + WS_Y1;
  float* y2     = ws + WS_Y2;
  __hip_bfloat16* y3b = (__hip_bfloat16*)(ws + WS_Y1);   // overlays dead y1

  zero_kernel<<<2,256,0,stream>>>(st);                    // sums (512 floats)
  transpose_kernel<<<512,256,0,stream>>>(pts, pts_t);
  fps_kernel<<<NB,256,0,stream>>>(xyz, nxyz, out);
  ballq_kernel<<<2048,256,0,stream>>>(xyz, nxyz, gidx);
  conv1_kernel<<<PTOT/256,256,0,stream>>>(xyz, pts_t, gidx, nxyz, w0, b0, y1);
  stats_kernel<<<dim3(64,32),256,0,stream>>>(y1, sum0, sq0);
  affine_kernel<<<1,64,0,stream>>>(sum0, sq0, g0, bt0, aA0, aB0, 64);
  conv2_kernel<<<PTOT/256,256,0,stream>>>(y1, aA0, aB0, w1, b1, y2);
  stats_kernel<<<dim3(64,32),256,0,stream>>>(y2, sum1, sq1);
  affine_kernel<<<1,64,0,stream>>>(sum1, sq1, g1, bt1, aA1, aB1, 64);
  conv3_kernel<<<PTOT/256,256,0,stream>>>(y2, aA1, aB1, w2, b2, y3b);
  statsmax_kernel<<<dim3(128,16),256,0,stream>>>(y3b, sum2, sq2, rawmax);
  affine_kernel<<<1,128,0,stream>>>(sum2, sq2, g2, bt2, aA2, aB2, 128);
  finalize_kernel<<<4096,256,0,stream>>>(rawmax, aA2, aB2, out + NB*3*NS);
}

// Round 5
// 567.202 us; speedup vs baseline: 1.3886x; 1.3886x over previous
//
#include <hip/hip_runtime.h>
#include <hip/hip_bf16.h>
#include <stdint.h>

#define NB 16
#define NPT 2048
#define NS 512
#define NK 32
#define PTOT (NB*NS*NK)   // 262144 positions
#define C_IN 67
#define EPSV 1e-5f

// ws layout (float indices)
#define WS_NEWXYZ 0            // 24576
#define WS_GIDX   24576        // ints, 262144 -> 286720
#define WS_STATS  286720       // 1024: sum0@0 sq0@64 sum1@128 sq1@192 sum2@256 sq2@384 aff@512..1024
#define WS_RAWMAX 294912       // 128*8192 = 1048576 -> 1343488
#define WS_PTS_T  1343488      // 2097152 -> 3440640
#define WS_Y1     3440640      // 64*PTOT bf16 = 8388608 floats -> 11829248
#define WS_Y2     11829248     // 8388608 -> 20217856
#define WS_Y3     20217856     // 128*PTOT bf16 = 16777216 floats -> 36995072 (148MB)

// ---- DPP 64-bit max step on a positive-double key: 2 dpp movs + v_max_f64 ----
template<int CTRL>
__device__ __forceinline__ double dppmax64f(double k){
  long long b = __double_as_longlong(k);
  int lo = (int)(uint32_t)b, hi = (int)(b>>32);
  int olo = __builtin_amdgcn_update_dpp(lo, lo, CTRL, 0xF, 0xF, false);
  int ohi = __builtin_amdgcn_update_dpp(hi, hi, CTRL, 0xF, 0xF, false);
  double o = __hiloint2double(ohi, olo);
  return fmax(o, k);
}

__device__ __forceinline__ unsigned long long u64max(unsigned long long a, unsigned long long b){ return a>b?a:b; }

__device__ __forceinline__ float bf2f(ushort u){ return __uint_as_float((uint32_t)u<<16); }

// ---------------- FPS (round-3 version, measured 223us) ----------------
// key = ((u64)dist_bits<<32) | (~n)  — as a positive double, u64 order == f64 order
__global__ __launch_bounds__(256) void fps_kernel(const float* __restrict__ xyz,
                                                  float* __restrict__ nxyz,
                                                  float* __restrict__ out0)
{
  __shared__ float4 lc[NPT];          // 32KB: xyz per point
  __shared__ double warr[2][4];
  __shared__ int sel[NS];
  const int b = blockIdx.x;
  const int tid = threadIdx.x;
  const float* xb = xyz + (size_t)b*3*NPT;
  float px[8], py[8], pz[8], dist[8];
  uint32_t lo_[8];
  #pragma unroll
  for (int j=0;j<8;j++){
    int n = j*256 + tid;
    float x = xb[n], y = xb[NPT+n], z = xb[2*NPT+n];
    lc[n] = make_float4(x,y,z,0.f);
    px[j]=x; py[j]=y; pz[j]=z; dist[j]=1e10f;
    lo_[j] = ~(uint32_t)n;
  }
  if (tid==0) sel[0]=0;
  __syncthreads();
  float4 c0 = lc[0];
  float cx = c0.x, cy = c0.y, cz = c0.z;
  const int lane = tid & 63, wid = tid >> 6;
  for (int t=1;t<NS;t++){
    double kk[8];
    #pragma unroll
    for (int j=0;j<8;j++){
      float dx = __fsub_rn(px[j], cx);
      float dy = __fsub_rn(py[j], cy);
      float dz = __fsub_rn(pz[j], cz);
      float d  = __fadd_rn(__fadd_rn(__fmul_rn(dx,dx),__fmul_rn(dy,dy)),__fmul_rn(dz,dz));
      float dd = fminf(dist[j], d);
      dist[j] = dd;
      kk[j] = __hiloint2double((int)__float_as_uint(dd), (int)lo_[j]);
    }
    double m0 = fmax(kk[0],kk[1]), m1 = fmax(kk[2],kk[3]);
    double m2 = fmax(kk[4],kk[5]), m3 = fmax(kk[6],kk[7]);
    double best = fmax(fmax(m0,m1), fmax(m2,m3));
    best = dppmax64f<0xB1>(best);    // quad xor1
    best = dppmax64f<0x4E>(best);    // quad xor2
    best = dppmax64f<0x124>(best);   // row_ror:4
    best = dppmax64f<0x128>(best);   // row_ror:8  -> each row16 has its max
    long long bb = __double_as_longlong(best);
    int bl = (int)(uint32_t)bb, bh = (int)(bb>>32);
    unsigned long long k0 = (((unsigned long long)(uint32_t)__builtin_amdgcn_readlane(bh, 0))<<32)  | (uint32_t)__builtin_amdgcn_readlane(bl, 0);
    unsigned long long k1 = (((unsigned long long)(uint32_t)__builtin_amdgcn_readlane(bh, 16))<<32) | (uint32_t)__builtin_amdgcn_readlane(bl, 16);
    unsigned long long k2 = (((unsigned long long)(uint32_t)__builtin_amdgcn_readlane(bh, 32))<<32) | (uint32_t)__builtin_amdgcn_readlane(bl, 32);
    unsigned long long k3 = (((unsigned long long)(uint32_t)__builtin_amdgcn_readlane(bh, 48))<<32) | (uint32_t)__builtin_amdgcn_readlane(bl, 48);
    unsigned long long kw = u64max(u64max(k0,k1), u64max(k2,k3));
    if (lane==0) warr[t&1][wid] = __longlong_as_double((long long)kw);
    __syncthreads();
    double w0 = warr[t&1][0], w1 = warr[t&1][1], w2 = warr[t&1][2], w3 = warr[t&1][3];
    double f = fmax(fmax(w0,w1), fmax(w2,w3));
    int n = (int)(~(uint32_t)__double_as_longlong(f));
    float4 cc = lc[n];
    cx = cc.x; cy = cc.y; cz = cc.z;
    if (tid==0) sel[t]=n;
  }
  __syncthreads();
  for (int s = tid; s < NS; s += 256){
    int n = sel[s];
    float4 cc = lc[n];
    float* np_ = nxyz + ((size_t)b*NS + s)*3;
    np_[0]=cc.x; np_[1]=cc.y; np_[2]=cc.z;
    float* ob = out0 + (size_t)b*3*NS + s;
    ob[0]=cc.x; ob[NS]=cc.y; ob[2*NS]=cc.z;
  }
}

// ---------------- ball query: one wave per group ----------------
__global__ __launch_bounds__(256) void ballq_kernel(const float* __restrict__ xyz,
                                                    const float* __restrict__ nxyz,
                                                    int* __restrict__ gidx)
{
  const int g = blockIdx.x*4 + (threadIdx.x>>6);
  const int lane = threadIdx.x & 63;
  const int b = g >> 9;
  const float* xb = xyz + (size_t)b*3*NPT;
  const float* c = nxyz + (size_t)g*3;
  const float cx = c[0], cy = c[1], cz = c[2];
  const float r2 = 0.2f*0.2f;
  int cnt = 0; int first = 0;
  int* out = gidx + (size_t)g*NK;
  for (int ch=0; ch<NPT/64 && cnt<NK; ch++){
    int n = ch*64 + lane;
    float dx = __fsub_rn(cx, xb[n]);
    float dy = __fsub_rn(cy, xb[NPT+n]);
    float dz = __fsub_rn(cz, xb[2*NPT+n]);
    float d  = __fadd_rn(__fadd_rn(__fmul_rn(dx,dx),__fmul_rn(dy,dy)),__fmul_rn(dz,dz));
    bool in = (d <= r2);
    unsigned long long mask = __ballot(in);
    if (mask){
      if (cnt==0) first = ch*64 + (__ffsll((unsigned long long)mask)-1);
      if (in){
        int pos = cnt + __popcll(mask & ((1ull<<lane)-1ull));
        if (pos < NK) out[pos] = n;
      }
      cnt += __popcll(mask);
    }
  }
  if (cnt < NK && lane >= cnt && lane < NK) out[lane] = first;
}

// ---------------- transpose points (B,64,N) -> (B,N,64) ----------------
__global__ __launch_bounds__(256) void transpose_kernel(const float* __restrict__ pts,
                                                        float* __restrict__ pts_t)
{
  __shared__ float tile[64][65];
  const int blk = blockIdx.x;          // B * N/64 = 512
  const int b = blk >> 5;
  const int n0 = (blk & 31) * 64;
  const int lane = threadIdx.x & 63;
  const int row4 = threadIdx.x >> 6;
  const float* src = pts + (size_t)b*64*NPT;
  #pragma unroll
  for (int r=0; r<16; r++){
    int cc = r*4 + row4;
    tile[cc][lane] = src[(size_t)cc*NPT + n0 + lane];
  }
  __syncthreads();
  float* dst = pts_t + ((size_t)b*NPT + n0)*64;
  #pragma unroll
  for (int r=0; r<16; r++){
    int nn = r*4 + row4;
    dst[(size_t)nn*64 + lane] = tile[lane][nn];
  }
}

// ---------------- conv1: gather + 67->64, bf16 out ----------------
__global__ __launch_bounds__(256) void conv1_kernel(const float* __restrict__ xyz,
    const float* __restrict__ pts_t, const int* __restrict__ gidx,
    const float* __restrict__ nxyz, const float* __restrict__ Wt,
    const float* __restrict__ bias, __hip_bfloat16* __restrict__ y1b)
{
  const int p = blockIdx.x*256 + threadIdx.x;
  const int bs = p >> 5;
  const int b = p >> 14;
  const int n = gidx[p];
  float x[C_IN];
  {
    const float* xb = xyz + (size_t)b*3*NPT;
    const float* cc = nxyz + (size_t)bs*3;
    x[0] = xb[n]        - cc[0];
    x[1] = xb[NPT+n]    - cc[1];
    x[2] = xb[2*NPT+n]  - cc[2];
    const float4* pr = (const float4*)(pts_t + ((size_t)b*NPT + n)*64);
    #pragma unroll
    for (int q=0;q<16;q++){
      float4 v = pr[q];
      x[3+4*q]=v.x; x[4+4*q]=v.y; x[5+4*q]=v.z; x[6+4*q]=v.w;
    }
  }
  #pragma unroll 1
  for (int o=0;o<64;o+=4){
    float a0=bias[o+0], a1=bias[o+1], a2=bias[o+2], a3=bias[o+3];
    #pragma unroll
    for (int c=0;c<C_IN;c++){
      float xv = x[c];
      a0 = fmaf(Wt[(o+0)*C_IN+c], xv, a0);
      a1 = fmaf(Wt[(o+1)*C_IN+c], xv, a1);
      a2 = fmaf(Wt[(o+2)*C_IN+c], xv, a2);
      a3 = fmaf(Wt[(o+3)*C_IN+c], xv, a3);
    }
    y1b[(size_t)(o+0)*PTOT+p]=__float2bfloat16(a0);
    y1b[(size_t)(o+1)*PTOT+p]=__float2bfloat16(a1);
    y1b[(size_t)(o+2)*PTOT+p]=__float2bfloat16(a2);
    y1b[(size_t)(o+3)*PTOT+p]=__float2bfloat16(a3);
  }
}

// ---------------- conv2: bf16 in (affine+relu), 64->64, bf16 out ----------------
__global__ __launch_bounds__(256) void conv2_kernel(const ushort* __restrict__ yin,
    const float* __restrict__ affA, const float* __restrict__ affB,
    const float* __restrict__ Wt, const float* __restrict__ bias,
    __hip_bfloat16* __restrict__ yout)
{
  const int p = blockIdx.x*256 + threadIdx.x;
  float x[64];
  #pragma unroll
  for (int c=0;c<64;c++){
    float v = bf2f(yin[(size_t)c*PTOT + p]);
    x[c] = fmaxf(fmaf(v, affA[c], affB[c]), 0.f);
  }
  #pragma unroll 1
  for (int o=0;o<64;o+=4){
    float a0=bias[o+0], a1=bias[o+1], a2=bias[o+2], a3=bias[o+3];
    #pragma unroll
    for (int c=0;c<64;c++){
      float xv = x[c];
      a0 = fmaf(Wt[(o+0)*64+c], xv, a0);
      a1 = fmaf(Wt[(o+1)*64+c], xv, a1);
      a2 = fmaf(Wt[(o+2)*64+c], xv, a2);
      a3 = fmaf(Wt[(o+3)*64+c], xv, a3);
    }
    yout[(size_t)(o+0)*PTOT+p]=__float2bfloat16(a0);
    yout[(size_t)(o+1)*PTOT+p]=__float2bfloat16(a1);
    yout[(size_t)(o+2)*PTOT+p]=__float2bfloat16(a2);
    yout[(size_t)(o+3)*PTOT+p]=__float2bfloat16(a3);
  }
}

// ---------------- conv3: bf16 in, 64->128, bf16 out ----------------
__global__ __launch_bounds__(256) void conv3_kernel(const ushort* __restrict__ yin,
    const float* __restrict__ affA, const float* __restrict__ affB,
    const float* __restrict__ Wt, const float* __restrict__ bias,
    __hip_bfloat16* __restrict__ y3b)
{
  const int p = blockIdx.x*256 + threadIdx.x;
  float x[64];
  #pragma unroll
  for (int c=0;c<64;c++){
    float v = bf2f(yin[(size_t)c*PTOT + p]);
    x[c] = fmaxf(fmaf(v, affA[c], affB[c]), 0.f);
  }
  #pragma unroll 1
  for (int o=0;o<128;o+=4){
    float a0=bias[o+0], a1=bias[o+1], a2=bias[o+2], a3=bias[o+3];
    #pragma unroll
    for (int c=0;c<64;c++){
      float xv = x[c];
      a0 = fmaf(Wt[(o+0)*64+c], xv, a0);
      a1 = fmaf(Wt[(o+1)*64+c], xv, a1);
      a2 = fmaf(Wt[(o+2)*64+c], xv, a2);
      a3 = fmaf(Wt[(o+3)*64+c], xv, a3);
    }
    y3b[(size_t)(o+0)*PTOT+p]=__float2bfloat16(a0);
    y3b[(size_t)(o+1)*PTOT+p]=__float2bfloat16(a1);
    y3b[(size_t)(o+2)*PTOT+p]=__float2bfloat16(a2);
    y3b[(size_t)(o+3)*PTOT+p]=__float2bfloat16(a3);
  }
}

// ---------------- per-channel sum / sumsq over bf16 ----------------
__global__ __launch_bounds__(256) void stats_bf16_kernel(const ushort* __restrict__ y,
                                                         float* __restrict__ sum,
                                                         float* __restrict__ sumsq)
{
  const int c = blockIdx.x;
  const ushort4* yc = (const ushort4*)(y + (size_t)c*PTOT + (size_t)blockIdx.y*8192);
  float s=0.f, s2=0.f;
  #pragma unroll 4
  for (int it=0; it<8; it++){
    ushort4 v = yc[it*256 + threadIdx.x];
    float f0=bf2f(v.x), f1=bf2f(v.y), f2=bf2f(v.z), f3=bf2f(v.w);
    s  += f0+f1+f2+f3;
    s2 += f0*f0+f1*f1+f2*f2+f3*f3;
  }
  #pragma unroll
  for (int off=32; off>0; off>>=1){ s += __shfl_down(s,off,64); s2 += __shfl_down(s2,off,64); }
  __shared__ float rs[4], rs2[4];
  const int lane = threadIdx.x&63, wid = threadIdx.x>>6;
  if (lane==0){ rs[wid]=s; rs2[wid]=s2; }
  __syncthreads();
  if (threadIdx.x==0){
    atomicAdd(sum+c,   rs[0]+rs[1]+rs[2]+rs[3]);
    atomicAdd(sumsq+c, rs2[0]+rs2[1]+rs2[2]+rs2[3]);
  }
}

// ---------------- fused stats + K-maxpool over bf16 y3 ----------------
__global__ __launch_bounds__(256) void statsmax_kernel(const __hip_bfloat16* __restrict__ y3b,
    float* __restrict__ sum, float* __restrict__ sumsq, float* __restrict__ rawmax)
{
  const int c = blockIdx.x;
  const int py0 = blockIdx.y*16384;               // position base
  const ushort* yc = (const ushort*)(y3b + (size_t)c*PTOT + py0);
  const int lane = threadIdx.x & 63, wid = threadIdx.x >> 6;
  const int grp = lane >> 3, sub = lane & 7;      // 8 lanes per bs-group
  float s=0.f, s2=0.f;
  #pragma unroll 2
  for (int it=0; it<16; it++){
    int bsl = it*32 + wid*8 + grp;                // local bs 0..511
    ushort4 v = *((const ushort4*)(yc + bsl*32) + sub);
    float f0=bf2f(v.x), f1=bf2f(v.y), f2=bf2f(v.z), f3=bf2f(v.w);
    s  += f0+f1+f2+f3;
    s2 += f0*f0+f1*f1+f2*f2+f3*f3;
    float m = fmaxf(fmaxf(f0,f1), fmaxf(f2,f3));
    m = fmaxf(m, __shfl_xor(m,1,64));
    m = fmaxf(m, __shfl_xor(m,2,64));
    m = fmaxf(m, __shfl_xor(m,4,64));
    if (sub==0) rawmax[(size_t)c*8192 + (py0>>5) + bsl] = m;
  }
  #pragma unroll
  for (int off=32; off>0; off>>=1){ s += __shfl_down(s,off,64); s2 += __shfl_down(s2,off,64); }
  __shared__ float rs[4], rs2[4];
  if (lane==0){ rs[wid]=s; rs2[wid]=s2; }
  __syncthreads();
  if (threadIdx.x==0){
    atomicAdd(sum+c,   rs[0]+rs[1]+rs[2]+rs[3]);
    atomicAdd(sumsq+c, rs2[0]+rs2[1]+rs2[2]+rs2[3]);
  }
}

__global__ void affine_kernel(const float* __restrict__ sum, const float* __restrict__ sumsq,
                              const float* __restrict__ g, const float* __restrict__ bt,
                              float* __restrict__ affA, float* __restrict__ affB, int C)
{
  int c = threadIdx.x;
  if (c < C){
    float mean = sum[c] * (1.f/PTOT);
    float var  = sumsq[c] * (1.f/PTOT) - mean*mean;
    float a = g[c] * rsqrtf(var + EPSV);
    affA[c] = a;
    affB[c] = fmaf(-mean, a, bt[c]);
  }
}

// ---------------- finalize: affine+relu on raw maxima ----------------
__global__ __launch_bounds__(256) void finalize_kernel(const float* __restrict__ rawmax,
    const float* __restrict__ affA, const float* __restrict__ affB,
    float* __restrict__ out)
{
  int i = blockIdx.x*256 + threadIdx.x;  // over 128*8192
  int c = i >> 13, r = i & 8191, b = r >> 9, s = r & 511;
  float a = affA[c], bb = affB[c];
  out[((size_t)(b*128+c))*512 + s] = fmaxf(fmaf(rawmax[i], a, bb), 0.f);
}

__global__ void zero_kernel(float* p){ p[blockIdx.x*256 + threadIdx.x] = 0.f; }

extern "C" void kernel_launch(void* const* d_in, const int* in_sizes, int n_in,
                              void* d_out, int out_size, void* d_ws, size_t ws_size,
                              hipStream_t stream) {
  const float* xyz = (const float*)d_in[0];
  const float* pts = (const float*)d_in[1];
  const float* w0  = (const float*)d_in[2];
  const float* b0  = (const float*)d_in[3];
  const float* g0  = (const float*)d_in[4];
  const float* bt0 = (const float*)d_in[5];
  const float* w1  = (const float*)d_in[6];
  const float* b1  = (const float*)d_in[7];
  const float* g1  = (const float*)d_in[8];
  const float* bt1 = (const float*)d_in[9];
  const float* w2  = (const float*)d_in[10];
  const float* b2  = (const float*)d_in[11];
  const float* g2  = (const float*)d_in[12];
  const float* bt2 = (const float*)d_in[13];
  float* out = (float*)d_out;
  float* ws  = (float*)d_ws;

  float* nxyz   = ws + WS_NEWXYZ;
  int*   gidx   = (int*)(ws + WS_GIDX);
  float* st     = ws + WS_STATS;
  float *sum0=st,     *sq0=st+64;
  float *sum1=st+128, *sq1=st+192;
  float *sum2=st+256, *sq2=st+384;
  float *aA0=st+512, *aB0=st+576, *aA1=st+640, *aB1=st+704;
  float *aA2=st+768, *aB2=st+896;
  float* rawmax = ws + WS_RAWMAX;
  float* pts_t  = ws + WS_PTS_T;
  __hip_bfloat16* y1b = (__hip_bfloat16*)(ws + WS_Y1);
  __hip_bfloat16* y2b = (__hip_bfloat16*)(ws + WS_Y2);
  __hip_bfloat16* y3b = (__hip_bfloat16*)(ws + WS_Y3);

  zero_kernel<<<2,256,0,stream>>>(st);                    // sums (512 floats)
  transpose_kernel<<<512,256,0,stream>>>(pts, pts_t);
  fps_kernel<<<NB,256,0,stream>>>(xyz, nxyz, out);
  ballq_kernel<<<2048,256,0,stream>>>(xyz, nxyz, gidx);
  conv1_kernel<<<PTOT/256,256,0,stream>>>(xyz, pts_t, gidx, nxyz, w0, b0, y1b);
  stats_bf16_kernel<<<dim3(64,32),256,0,stream>>>((const ushort*)y1b, sum0, sq0);
  affine_kernel<<<1,64,0,stream>>>(sum0, sq0, g0, bt0, aA0, aB0, 64);
  conv2_kernel<<<PTOT/256,256,0,stream>>>((const ushort*)y1b, aA0, aB0, w1, b1, y2b);
  stats_bf16_kernel<<<dim3(64,32),256,0,stream>>>((const ushort*)y2b, sum1, sq1);
  affine_kernel<<<1,64,0,stream>>>(sum1, sq1, g1, bt1, aA1, aB1, 64);
  conv3_kernel<<<PTOT/256,256,0,stream>>>((const ushort*)y2b, aA1, aB1, w2, b2, y3b);
  statsmax_kernel<<<dim3(128,16),256,0,stream>>>(y3b, sum2, sq2, rawmax);
  affine_kernel<<<1,128,0,stream>>>(sum2, sq2, g2, bt2, aA2, aB2, 128);
  finalize_kernel<<<4096,256,0,stream>>>(rawmax, aA2, aB2, out + NB*3*NS);
}